// Round 8
// baseline (939.147 us; speedup 1.0000x reference)
//
#include <hip/hip_runtime.h>
#include <math.h>

// ---------------------------------------------------------------------------
// WaveNet inference, fp32, right-aligned suffix computation.
// Round 11 == round 10 resubmit (container failed twice = infra flake; kernel
// re-audited: all LDS/global accesses in-bounds, no hang paths).
// Round 10: explicit software pipelining. Rounds 7-9 all ~94-97us, VALUBusy
// ~50%, VGPR 28 -> compiler keeps <=2 loads in flight; latency-stalled on
// L1 weight stream. Now: hand-pipelined depth-2 A/B buffer rotation, 2-ic
// chunks (fg) / 4-ic chunks (res), pointer-increment addressing (imm offsets
// <=384B), unroll-1 steady-state loops (I$ ~2KB/layer), ~115 VGPR (<=128 so
// 2 blocks/CU resident). FMA order per acc unchanged (ic asc, a then c) ->
// absmax must stay 2.4e-4.
// Residual taps stay preloaded PRE-BAR1 (phase B must not read Xs: other
// threads' in-place X writes follow phase B with no barrier).
// Chain: 8188 -h-> 8157 -t-> 7165 -h-> 7134 -t-> 6142 -h-> 6111 -t-> 5119
//        -h-> 5088 -t-> 4096.  Layer 39 (last tail, s=4) emits h only.
// ---------------------------------------------------------------------------

#define TS   8192
#define T0   8188
#define NB   8
#define RCH  32
#define CLS  256
#define TOUT 4096

// workspace layout (float offsets)
#define OFF_WBLOB 0                      // 40 * 5120  (wf[ic][k][oc], wg, wr[ic][oc])
#define OFF_ST    204800                 // start_w^T  [ic][oc]
#define OFF_SK    212992                 // skip_w[39]^T [dc][sc]
#define OFF_E1T   221184                 // end1^T [sc][ec]
#define OFF_E2T   286720                 // end2^T [ec][cc]
#define OFF_XA    352256                 // NB*RCH*TS   (normal layout)
#define OFF_XSUB  (OFF_XA + NB*RCH*TS)   // NB*32*32*256 (sub layout)
#define OFF_H1    (OFF_XSUB + NB*RCH*TS) // NB*256*TOUT
#define OFF_E1    (OFF_H1 + NB*256*TOUT)

#define XW 144                           // Xs row stride
#define HW 130                           // Hs row stride

__device__ __forceinline__ float tanh_fast(float x) {
    float e = __expf(2.0f * x);
    return 1.0f - 2.0f / (e + 1.0f);
}
__device__ __forceinline__ float sigmoid_fast(float x) {
    return 1.0f / (1.0f + __expf(-x));
}

// ---------------------------------------------------------------------------
__global__ void repack_kernel(const float* __restrict__ start_w,
                              const float* __restrict__ filter_w,
                              const float* __restrict__ gate_w,
                              const float* __restrict__ residual_w,
                              const float* __restrict__ skip_w,
                              const float* __restrict__ end1_w,
                              const float* __restrict__ end2_w,
                              float* __restrict__ ws) {
    int id = blockIdx.x * 256 + threadIdx.x;
    if (id < 204800) {
        int l = id / 5120, r = id % 5120;
        float v;
        if (r < 4096) {                      // wf then wg: [ic][k][oc]
            const float* src = (r < 2048) ? filter_w : gate_w;
            int rr = r & 2047;
            int ic = rr >> 6, k = (rr >> 5) & 1, oc = rr & 31;
            v = src[((l * 32 + oc) * 32 + ic) * 2 + k];
        } else {                             // wr: [ic][oc]
            int rr = r - 4096;
            int ic = rr >> 5, oc = rr & 31;
            v = residual_w[(l * 32 + oc) * 32 + ic];
        }
        ws[OFF_WBLOB + id] = v;
    } else if (id < 204800 + 8192) {
        int r = id - 204800;
        int ic = r >> 5, oc = r & 31;
        ws[OFF_ST + r] = start_w[oc * 256 + ic];
    } else if (id < 212992 + 8192) {
        int r = id - 212992;
        int dc = r >> 8, sc = r & 255;
        ws[OFF_SK + r] = skip_w[(39 * 256 + sc) * 32 + dc];
    } else if (id < 221184 + 65536) {
        int r = id - 221184;
        int sc = r >> 8, ec = r & 255;
        ws[OFF_E1T + r] = end1_w[ec * 256 + sc];
    } else if (id < 286720 + 65536) {
        int r = id - 286720;
        int ec = r >> 8, cc = r & 255;
        ws[OFF_E2T + r] = end2_w[cc * 256 + ec];
    }
}

// ---------------------------------------------------------------------------
// start conv, 16 outputs/thread; weights vector-loaded (vz trick)
__global__ __launch_bounds__(256) void start_kernel(const float* __restrict__ xin,
                                                    const float* __restrict__ st,
                                                    float* __restrict__ xout) {
    __shared__ int zs;
    if (threadIdx.x == 0) zs = 0;
    __syncthreads();
    const int vz = zs;                       // runtime 0, compiler-opaque
    int t = blockIdx.x * 256 + threadIdx.x;
    int og = blockIdx.y;                     // 0..1 (16 oc each)
    int b = blockIdx.z;
    if (t >= T0) return;
    const float* xi = xin + (size_t)b * 256 * 16384 + (16384 - T0) + t;
    const float* wb = st + vz + og * 16;
    float acc[16];
#pragma unroll
    for (int c = 0; c < 16; c++) acc[c] = 0.f;
#pragma unroll 4
    for (int ic = 0; ic < 256; ic++) {
        float xv = xi[ic * 16384];
        const float* w = wb + ic * 32;
        const float4 w0 = *(const float4*)(w);
        const float4 w1 = *(const float4*)(w + 4);
        const float4 w2 = *(const float4*)(w + 8);
        const float4 w3 = *(const float4*)(w + 12);
        const float ww[16] = {w0.x,w0.y,w0.z,w0.w, w1.x,w1.y,w1.z,w1.w,
                              w2.x,w2.y,w2.z,w2.w, w3.x,w3.y,w3.z,w3.w};
#pragma unroll
        for (int c = 0; c < 16; c++) acc[c] = fmaf(ww[c], xv, acc[c]);
    }
    float* xo = xout + ((size_t)(b * RCH) + og * 16) * TS + t;
#pragma unroll
    for (int c = 0; c < 16; c++) xo[c * TS] = acc[c];
}

// ---------------------------------------------------------------------------
// fg pipeline fragment: 2 ic worth of weights (8 float4) + taps (4 float2)
struct WFrag {
    float4 wa0, wc0, ga0, gc0, wa1, wc1, ga1, gc1;
    float2 a0t, c0t, a1t, c1t;
};

__device__ __forceinline__ void load_w(WFrag& W, const float* pf, const float* pg,
                                       const float* px_, int d) {
    W.wa0 = *(const float4*)(pf);
    W.wc0 = *(const float4*)(pf + 32);
    W.wa1 = *(const float4*)(pf + 64);
    W.wc1 = *(const float4*)(pf + 96);
    W.ga0 = *(const float4*)(pg);
    W.gc0 = *(const float4*)(pg + 32);
    W.ga1 = *(const float4*)(pg + 64);
    W.gc1 = *(const float4*)(pg + 96);
    W.a0t = *(const float2*)(px_);
    W.c0t = (d == 1) ? *(const float2*)(px_ + 2) : *(const float2*)(px_ + d);
    W.a1t = *(const float2*)(px_ + XW);
    W.c1t = (d == 1) ? *(const float2*)(px_ + XW + 2) : *(const float2*)(px_ + XW + d);
}

__device__ __forceinline__ void fma_w(const WFrag& W, int d,
                                      float f0[4], float g0[4],
                                      float f1[4], float g1[4]) {
    {   // ic = even
        const float a0v = W.a0t.x, a1v = W.a0t.y;
        const float c0v = (d == 1) ? W.a0t.y : W.c0t.x;
        const float c1v = (d == 1) ? W.c0t.x : W.c0t.y;
        const float wa_[4] = {W.wa0.x, W.wa0.y, W.wa0.z, W.wa0.w};
        const float wc_[4] = {W.wc0.x, W.wc0.y, W.wc0.z, W.wc0.w};
        const float ga_[4] = {W.ga0.x, W.ga0.y, W.ga0.z, W.ga0.w};
        const float gc_[4] = {W.gc0.x, W.gc0.y, W.gc0.z, W.gc0.w};
#pragma unroll
        for (int j = 0; j < 4; ++j) {
            f0[j] = fmaf(wa_[j], a0v, f0[j]);
            f0[j] = fmaf(wc_[j], c0v, f0[j]);
            g0[j] = fmaf(ga_[j], a0v, g0[j]);
            g0[j] = fmaf(gc_[j], c0v, g0[j]);
            f1[j] = fmaf(wa_[j], a1v, f1[j]);
            f1[j] = fmaf(wc_[j], c1v, f1[j]);
            g1[j] = fmaf(ga_[j], a1v, g1[j]);
            g1[j] = fmaf(gc_[j], c1v, g1[j]);
        }
    }
    {   // ic = odd
        const float a0v = W.a1t.x, a1v = W.a1t.y;
        const float c0v = (d == 1) ? W.a1t.y : W.c1t.x;
        const float c1v = (d == 1) ? W.c1t.x : W.c1t.y;
        const float wa_[4] = {W.wa1.x, W.wa1.y, W.wa1.z, W.wa1.w};
        const float wc_[4] = {W.wc1.x, W.wc1.y, W.wc1.z, W.wc1.w};
        const float ga_[4] = {W.ga1.x, W.ga1.y, W.ga1.z, W.ga1.w};
        const float gc_[4] = {W.gc1.x, W.gc1.y, W.gc1.z, W.gc1.w};
#pragma unroll
        for (int j = 0; j < 4; ++j) {
            f0[j] = fmaf(wa_[j], a0v, f0[j]);
            f0[j] = fmaf(wc_[j], c0v, f0[j]);
            g0[j] = fmaf(ga_[j], a0v, g0[j]);
            g0[j] = fmaf(gc_[j], c0v, g0[j]);
            f1[j] = fmaf(wa_[j], a1v, f1[j]);
            f1[j] = fmaf(wc_[j], c1v, f1[j]);
            g1[j] = fmaf(ga_[j], a1v, g1[j]);
            g1[j] = fmaf(gc_[j], c1v, g1[j]);
        }
    }
}

// residual pipeline fragment: 4 ic (4 float4 weights + 4 float2 h)
struct RFrag {
    float4 w0, w1, w2, w3;
    float2 h0, h1, h2v, h3;
};

__device__ __forceinline__ void load_r(RFrag& R, const float* pr, const float* ph) {
    R.w0 = *(const float4*)(pr);
    R.w1 = *(const float4*)(pr + 32);
    R.w2 = *(const float4*)(pr + 64);
    R.w3 = *(const float4*)(pr + 96);
    R.h0 = *(const float2*)(ph);
    R.h1 = *(const float2*)(ph + HW);
    R.h2v = *(const float2*)(ph + 2 * HW);
    R.h3 = *(const float2*)(ph + 3 * HW);
}

__device__ __forceinline__ void fma_r(const RFrag& R, float r0[4], float r1[4]) {
#pragma unroll
    for (int u = 0; u < 4; ++u) {
        const float4 wv = (u == 0) ? R.w0 : (u == 1) ? R.w1 : (u == 2) ? R.w2 : R.w3;
        const float2 hv = (u == 0) ? R.h0 : (u == 1) ? R.h1 : (u == 2) ? R.h2v : R.h3;
        const float wv_[4] = {wv.x, wv.y, wv.z, wv.w};
#pragma unroll
        for (int j = 0; j < 4; ++j) {
            r0[j] = fmaf(wv_[j], hv.x, r0[j]);
            r1[j] = fmaf(wv_[j], hv.y, r1[j]);
        }
    }
}

// ---------------------------------------------------------------------------
// 5 fused layers (dil 1,2,4,8,16). Block (64,8): wave = 4-oc group, 96 output
// positions/block (tile 127). Thread = positions 2tx, 2tx+1. Single in-place
// X buffer: all X reads pre-BAR1 (incl. residual taps); X writes post-phase-B.
// Software-pipelined inner loops (depth-2 A/B rotation).
// MODE 0: head (X normal -> Xsub). MODE 1: tail (Xsub -> X).
// MODE 2: tail-last (layer s=4 emits h only).
template<int MODE>
__global__ __launch_bounds__(512, 4) void five_kernel(const float* __restrict__ in,
                                                      float* __restrict__ outp,
                                                      const float* __restrict__ wl,
                                                      int Tin) {
    __shared__ float Xs[32 * XW];
    __shared__ float Hs[32 * HW];
    __shared__ int zsh;
    const int tx  = threadIdx.x;
    const int cg  = __builtin_amdgcn_readfirstlane(threadIdx.y);   // 0..7
    const int oc0 = cg * 4;
    const int c0  = blockIdx.x * 96;
    const int b   = (MODE == 0) ? blockIdx.y : blockIdx.z;
    const int r   = (MODE == 0) ? 0 : blockIdx.y;
    const int L   = (MODE == 0) ? Tin : ((Tin - r + 31) >> 5);
    const int Lw  = min(127, L - c0);
    const int px  = tx * 2;                  // positions px, px+1

    if (tx == 0 && threadIdx.y == 0) zsh = 0;

    // coalesced tile load (head: stride-1 in t; tail: stride-1 in subseq idx)
    const float* src = in + (size_t)b * 262144 + (size_t)r * 256 + c0;
    for (int ch = cg; ch < 32; ch += 8)
        for (int p = tx; p < Lw; p += 64)
            Xs[ch * XW + p] = src[(size_t)ch * 8192 + p];
    __syncthreads();
    const float* wlv = wl + zsh;             // runtime ==wl; VGPR addressing

    int w = Lw;
#pragma unroll
    for (int s = 0; s < 5; ++s) {
        const int d  = 1 << s;               // constexpr per unrolled iter
        const int nw = w - d;
        const float* wb0 = wlv + s * 5120;   // wf | wg +2048 | wr +4096

        // residual taps X[p+d], preloaded PRE-BAR1 (see header comment)
        float tA[4], tB[4];
        if (!(MODE == 2 && s == 4)) {
#pragma unroll
            for (int j = 0; j < 4; ++j) {
                const float* xr = Xs + (oc0 + j) * XW + px;
                if (d == 1) {
                    const float2 u = *(const float2*)(xr);
                    const float2 v = *(const float2*)(xr + 2);
                    tA[j] = u.y; tB[j] = v.x;
                } else {
                    const float2 u = *(const float2*)(xr + d);
                    tA[j] = u.x; tB[j] = u.y;
                }
            }
        }

        float f0[4], g0[4], f1[4], g1[4];
#pragma unroll
        for (int j = 0; j < 4; ++j) { f0[j]=0.f; g0[j]=0.f; f1[j]=0.f; g1[j]=0.f; }

        // ---- phase A: fg conv, 16 chunks x 2 ic, depth-2 A/B pipeline ----
        {
            const float* pf  = wb0 + oc0;
            const float* pg  = wb0 + 2048 + oc0;
            const float* pxp = Xs + px;
            WFrag A, B;
            load_w(A, pf, pg, pxp, d);  pf += 128; pg += 128; pxp += 2 * XW;
            load_w(B, pf, pg, pxp, d);  pf += 128; pg += 128; pxp += 2 * XW;
#pragma unroll 1
            for (int k = 0; k < 7; ++k) {
                fma_w(A, d, f0, g0, f1, g1);
                load_w(A, pf, pg, pxp, d);  pf += 128; pg += 128; pxp += 2 * XW;
                fma_w(B, d, f0, g0, f1, g1);
                load_w(B, pf, pg, pxp, d);  pf += 128; pg += 128; pxp += 2 * XW;
            }
            fma_w(A, d, f0, g0, f1, g1);
            fma_w(B, d, f0, g0, f1, g1);
        }

        float h0[4], h1[4];
#pragma unroll
        for (int j = 0; j < 4; ++j) {
            h0[j] = tanh_fast(f0[j]) * sigmoid_fast(g0[j]);
            h1[j] = tanh_fast(f1[j]) * sigmoid_fast(g1[j]);
        }

        if (MODE == 2 && s == 4) {               // layer 39: h only, reg-direct
            if (px < nw) {
                float* dst = outp + (size_t)b * 262144 + (size_t)(((c0 + px) << 5) + r);
#pragma unroll
                for (int j = 0; j < 4; ++j) dst[(size_t)(oc0 + j) * 8192] = h0[j];
            }
            if (px + 1 < nw) {
                float* dst = outp + (size_t)b * 262144 + (size_t)(((c0 + px + 1) << 5) + r);
#pragma unroll
                for (int j = 0; j < 4; ++j) dst[(size_t)(oc0 + j) * 8192] = h1[j];
            }
            return;
        }

        // Hs write (unpredicated: positions >= nw are dead garbage)
#pragma unroll
        for (int j = 0; j < 4; ++j)
            *(float2*)(Hs + (oc0 + j) * HW + px) = make_float2(h0[j], h1[j]);
        __syncthreads();   // BAR1: all X reads + H writes complete

        float r0[4], r1[4];
#pragma unroll
        for (int j = 0; j < 4; ++j) { r0[j] = tA[j]; r1[j] = tB[j]; }

        // ---- phase B: residual conv, 8 chunks x 4 ic, depth-2 pipeline ----
        {
            const float* pr = wb0 + 4096 + oc0;
            const float* ph = Hs + px;
            RFrag RA, RB;
            load_r(RA, pr, ph);  pr += 128; ph += 4 * HW;
            load_r(RB, pr, ph);  pr += 128; ph += 4 * HW;
#pragma unroll 1
            for (int k = 0; k < 3; ++k) {
                fma_r(RA, r0, r1);
                load_r(RA, pr, ph);  pr += 128; ph += 4 * HW;
                fma_r(RB, r0, r1);
                load_r(RB, pr, ph);  pr += 128; ph += 4 * HW;
            }
            fma_r(RA, r0, r1);
            fma_r(RB, r0, r1);
        }

        if (s == 4) {                            // final: reg-direct global store
            if (MODE == 0) {                     // -> Xsub[b][oc][t&31][t>>5]
                if (px < nw) {
                    const int t = c0 + px;
                    float* dst = outp + (size_t)b * 262144 + (size_t)(t & 31) * 256 + (t >> 5);
#pragma unroll
                    for (int j = 0; j < 4; ++j) dst[(size_t)(oc0 + j) * 8192] = r0[j];
                }
                if (px + 1 < nw) {
                    const int t = c0 + px + 1;
                    float* dst = outp + (size_t)b * 262144 + (size_t)(t & 31) * 256 + (t >> 5);
#pragma unroll
                    for (int j = 0; j < 4; ++j) dst[(size_t)(oc0 + j) * 8192] = r1[j];
                }
            } else {                             // -> X[b][oc][32*p + r]
                if (px < nw) {
                    float* dst = outp + (size_t)b * 262144 + (size_t)(((c0 + px) << 5) + r);
#pragma unroll
                    for (int j = 0; j < 4; ++j) dst[(size_t)(oc0 + j) * 8192] = r0[j];
                }
                if (px + 1 < nw) {
                    float* dst = outp + (size_t)b * 262144 + (size_t)(((c0 + px + 1) << 5) + r);
#pragma unroll
                    for (int j = 0; j < 4; ++j) dst[(size_t)(oc0 + j) * 8192] = r1[j];
                }
            }
        } else {                                 // in-place X update (b64)
#pragma unroll
            for (int j = 0; j < 4; ++j)
                *(float2*)(Xs + (oc0 + j) * XW + px) = make_float2(r0[j], r1[j]);
            __syncthreads();                     // BAR2: X writes visible
        }
        w = nw;
    }
}

// ---------------------------------------------------------------------------
// skip conv + relu, 32 outputs/thread; weights vector-loaded (vz trick)
__global__ __launch_bounds__(256) void skip_kernel(const float* __restrict__ xin,
                                                   const float* __restrict__ sk,
                                                   float* __restrict__ h1) {
    __shared__ int zs;
    if (threadIdx.x == 0) zs = 0;
    __syncthreads();
    const int vz = zs;
    int t = blockIdx.x * 256 + threadIdx.x;
    int sg = blockIdx.y;                     // 8 groups of 32
    int b = blockIdx.z;
    const float* xi = xin + (size_t)(b * RCH) * TS + t;
    const float* wb = sk + vz + sg * 32;
    float acc[32];
#pragma unroll
    for (int j = 0; j < 32; j++) acc[j] = 0.f;
#pragma unroll 4
    for (int dc = 0; dc < 32; dc++) {
        float xv = xi[dc * TS];
        const float* w = wb + dc * 256;
#pragma unroll
        for (int q = 0; q < 8; q++) {
            const float4 w4 = *(const float4*)(w + q * 4);
            acc[q*4+0] = fmaf(w4.x, xv, acc[q*4+0]);
            acc[q*4+1] = fmaf(w4.y, xv, acc[q*4+1]);
            acc[q*4+2] = fmaf(w4.z, xv, acc[q*4+2]);
            acc[q*4+3] = fmaf(w4.w, xv, acc[q*4+3]);
        }
    }
    float* ho = h1 + ((size_t)(b * 256) + sg * 32) * TOUT + t;
#pragma unroll
    for (int j = 0; j < 32; j++) ho[j * TOUT] = fmaxf(acc[j], 0.f);
}

// end1 + bias + relu, 32 outputs/thread; weights vector-loaded
__global__ __launch_bounds__(256) void end1_kernel(const float* __restrict__ h1,
                                                   const float* __restrict__ e1t,
                                                   const float* __restrict__ b1,
                                                   float* __restrict__ e1) {
    __shared__ int zs;
    if (threadIdx.x == 0) zs = 0;
    __syncthreads();
    const int vz = zs;
    int t = blockIdx.x * 256 + threadIdx.x;
    int eg = blockIdx.y;                     // 8 groups of 32
    int b = blockIdx.z;
    const float* hp = h1 + (size_t)(b * 256) * TOUT + t;
    const float* wb = e1t + vz + eg * 32;
    float acc[32];
#pragma unroll
    for (int j = 0; j < 32; j++) acc[j] = b1[eg * 32 + j];
#pragma unroll 4
    for (int sc = 0; sc < 256; sc++) {
        float xv = hp[sc * TOUT];
        const float* w = wb + sc * 256;
#pragma unroll
        for (int q = 0; q < 8; q++) {
            const float4 w4 = *(const float4*)(w + q * 4);
            acc[q*4+0] = fmaf(w4.x, xv, acc[q*4+0]);
            acc[q*4+1] = fmaf(w4.y, xv, acc[q*4+1]);
            acc[q*4+2] = fmaf(w4.z, xv, acc[q*4+2]);
            acc[q*4+3] = fmaf(w4.w, xv, acc[q*4+3]);
        }
    }
    float* ep = e1 + ((size_t)(b * 256) + eg * 32) * TOUT + t;
#pragma unroll
    for (int j = 0; j < 32; j++) ep[j * TOUT] = fmaxf(acc[j], 0.f);
}

// end2 + bias, transposed store, 32 outputs/thread; weights vector-loaded
__global__ __launch_bounds__(256) void end2_kernel(const float* __restrict__ e1,
                                                   const float* __restrict__ e2t,
                                                   const float* __restrict__ b2,
                                                   float* __restrict__ out) {
    __shared__ int zs;
    if (threadIdx.x == 0) zs = 0;
    __syncthreads();
    const int vz = zs;
    int t = blockIdx.x * 256 + threadIdx.x;
    int cg = blockIdx.y;                     // 8 groups of 32
    int b = blockIdx.z;
    const float* ep = e1 + (size_t)(b * 256) * TOUT + t;
    const float* wb = e2t + vz + cg * 32;
    float acc[32];
#pragma unroll
    for (int j = 0; j < 32; j++) acc[j] = b2[cg * 32 + j];
#pragma unroll 4
    for (int ec = 0; ec < 256; ec++) {
        float xv = ep[ec * TOUT];
        const float* w = wb + ec * 256;
#pragma unroll
        for (int q = 0; q < 8; q++) {
            const float4 w4 = *(const float4*)(w + q * 4);
            acc[q*4+0] = fmaf(w4.x, xv, acc[q*4+0]);
            acc[q*4+1] = fmaf(w4.y, xv, acc[q*4+1]);
            acc[q*4+2] = fmaf(w4.z, xv, acc[q*4+2]);
            acc[q*4+3] = fmaf(w4.w, xv, acc[q*4+3]);
        }
    }
    float* op = out + ((size_t)(b * TOUT + t)) * CLS + cg * 32;
#pragma unroll
    for (int j = 0; j < 8; j++)
        ((float4*)op)[j] = make_float4(acc[4*j], acc[4*j+1], acc[4*j+2], acc[4*j+3]);
}

// ---------------------------------------------------------------------------
extern "C" void kernel_launch(void* const* d_in, const int* in_sizes, int n_in,
                              void* d_out, int out_size, void* d_ws, size_t ws_size,
                              hipStream_t stream) {
    const float* x_input    = (const float*)d_in[0];
    const float* start_w    = (const float*)d_in[1];
    const float* filter_w   = (const float*)d_in[2];
    const float* gate_w     = (const float*)d_in[3];
    const float* residual_w = (const float*)d_in[4];
    const float* skip_w     = (const float*)d_in[5];
    const float* end1_w     = (const float*)d_in[6];
    const float* end1_b     = (const float*)d_in[7];
    const float* end2_w     = (const float*)d_in[8];
    const float* end2_b     = (const float*)d_in[9];
    float* ws  = (float*)d_ws;
    float* out = (float*)d_out;

    repack_kernel<<<dim3((352256 + 255) / 256), 256, 0, stream>>>(
        start_w, filter_w, gate_w, residual_w, skip_w, end1_w, end2_w, ws);

    start_kernel<<<dim3(32, 2, NB), 256, 0, stream>>>(
        x_input, ws + OFF_ST, ws + OFF_XA);

    float* xa   = ws + OFF_XA;
    float* xsub = ws + OFF_XSUB;
    int Tin = T0;                            // 8188
    for (int sb = 0; sb < 4; ++sb) {
        const float* wb = ws + OFF_WBLOB + (size_t)sb * 51200;
        const int Th  = Tin - 31;            // head output length
        const int nbh = (Th + 95) / 96;
        five_kernel<0><<<dim3(nbh, NB), dim3(64, 8), 0, stream>>>(xa, xsub, wb, Tin);

        const int Lmax  = (Th + 31) >> 5;    // longest residue subsequence
        const int LoutM = Lmax - 31;
        const int nbt   = (LoutM + 95) / 96;
        if (sb < 3)
            five_kernel<1><<<dim3(nbt, 32, NB), dim3(64, 8), 0, stream>>>(xsub, xa, wb + 25600, Th);
        else
            five_kernel<2><<<dim3(nbt, 32, NB), dim3(64, 8), 0, stream>>>(xsub, xa, wb + 25600, Th);
        Tin = Th - 992;
    }
    // Tin == 4096; layer-39 h in xa

    skip_kernel<<<dim3(16, 8, NB), 256, 0, stream>>>(xa, ws + OFF_SK, ws + OFF_H1);
    end1_kernel<<<dim3(16, 8, NB), 256, 0, stream>>>(ws + OFF_H1, ws + OFF_E1T, end1_b, ws + OFF_E1);
    end2_kernel<<<dim3(16, 8, NB), 256, 0, stream>>>(ws + OFF_E1, ws + OFF_E2T, end2_b, out);
}